// Round 21
// baseline (135.954 us; speedup 1.0000x reference)
//
#include <hip/hip_runtime.h>
#include <hip/hip_bf16.h>

#define D_FEAT 128
#define BIN_SHIFT 4
#define NODES_PER_BIN 16       // fine bins: 16 nodes -> 3125 bins at N=50k
#define BCAP 1024              // slots per bin; mean load 192 at E=600k
#define NB_MAX 3200            // LDS hist capacity in k1
#define T1 512
#define BINB 256               // uniform edge-range binning blocks
#define RMAX 8                 // max edge rounds per bin block (E <= 1M)
#define CSR_CAP 1280           // 1024 + 16*16 pad slots
#define OVF_CAP 4096           // overflow side-list (expected use: 0)

typedef float f2v __attribute__((ext_vector_type(2)));

// round-to-nearest-even fp32 -> bf16 bits
__device__ __forceinline__ unsigned bf16_rne(float f) {
    unsigned u = __float_as_uint(f);
    return (u + 0x7fffu + ((u >> 16) & 1u)) >> 16;
}

// ---- fast kernel 1: fused h->bf16 conversion + uniform-range fine binning ----
// Blocks [0, convBlocks): convert h (fp32) -> hb (packed bf16 pairs).
// Blocks [convBlocks, convBlocks+BINB): each takes a UNIFORM edge range
// (~E/256 edges) -> LDS histogram over 3125 fine bins -> one cursor
// reservation round -> direct scatter. Uniform ranges kill the bin-block
// tail (was 293 blocks -> 2x integer-round wall); 3125 cursor addresses
// shorten per-address atomic chains ~390 -> ~135.
__global__ void __launch_bounds__(T1)
conv_bin_kernel(const float* __restrict__ h,
                const int* __restrict__ src, const int* __restrict__ dst,
                const float* __restrict__ dt, const float* __restrict__ norm,
                const float* __restrict__ decay_lam,
                unsigned* __restrict__ hb,
                int* __restrict__ bin_cursor, unsigned long long* __restrict__ binned,
                int* __restrict__ ovf_cnt, int* __restrict__ ovf_d,
                int* __restrict__ ovf_s, float* __restrict__ ovf_w,
                int E, int HN4, int convBlocks, int NB) {
    __shared__ unsigned hist[NB_MAX];
    __shared__ unsigned cur[NB_MAX];
    __shared__ unsigned gbase[NB_MAX];

    int t = threadIdx.x;
    if (blockIdx.x < convBlocks) {
        int i = blockIdx.x * T1 + t;
        if (i < HN4) {
            float4 v = ((const float4*)h)[i];
            ((uint2*)hb)[i] = make_uint2(bf16_rne(v.x) | (bf16_rne(v.y) << 16),
                                         bf16_rne(v.z) | (bf16_rne(v.w) << 16));
        }
        return;
    }

    int blk = blockIdx.x - convBlocks;                 // 0..BINB-1
    int e_begin = (int)((long long)blk * E / BINB);
    int e_end   = (int)((long long)(blk + 1) * E / BINB);
    int cnt_e   = e_end - e_begin;                     // ~E/256, uniform

    for (int i = t; i < NB; i += T1) { hist[i] = 0; cur[i] = 0; }
    __syncthreads();

    float lam = fmaxf(decay_lam[0], 0.0f) + 1e-4f;

    unsigned long long ent[RMAX];
    int bn[RMAX];
    #pragma unroll
    for (int k = 0; k < RMAX; ++k) {
        int i = k * T1 + t;
        bn[k] = -1;
        if (i < cnt_e) {
            int e = e_begin + i;
            int s = src[e], d = dst[e];
            float w = norm[e] * expf(-lam * dt[e]);
            int b = d >> BIN_SHIFT;
            int l = d & (NODES_PER_BIN - 1);
            ent[k] = ((unsigned long long)l << 32) | (((unsigned)s << 16) | bf16_rne(w));
            bn[k] = b;
            atomicAdd(&hist[b], 1u);
        }
    }
    __syncthreads();

    for (int i = t; i < NB; i += T1)
        if (hist[i] > 0)
            gbase[i] = (unsigned)atomicAdd(&bin_cursor[i], (int)hist[i]);
    __syncthreads();

    #pragma unroll
    for (int k = 0; k < RMAX; ++k) {
        if (bn[k] >= 0) {
            int b = bn[k];
            unsigned gp = gbase[b] + atomicAdd(&cur[b], 1u);
            if (gp < BCAP) {
                binned[(size_t)b * BCAP + gp] = ent[k];
            } else {                               // bin region full (expected: never)
                int o = atomicAdd(ovf_cnt, 1);
                if (o < OVF_CAP) {
                    int l = (int)(ent[k] >> 32);
                    ovf_d[o] = (b << BIN_SHIFT) | l;
                    ovf_s[o] = (int)((ent[k] >> 16) & 0xFFFFu);
                    ovf_w[o] = __uint_as_float(((unsigned)ent[k] & 0xFFFFu) << 16);
                }
            }
        }
    }
}

// ---- fast kernel 2: 1-WAVE per 16-node bin, counting-sort + deep-MLP gather ----
// 3125 blocks x 64 threads, ~5.3KB LDS each -> ~12 blocks/CU ALL co-resident
// from t=0 (R13/R14 showed OccupancyPercent 23% = integer-round tail of the
// 391-block layout; this kills the tail: wall ~ max-block not 2x avg).
// Per wave: sort its bin's ~192 entries into a x16-padded LDS CSR (pad =
// src0/w+0 no-op edges), then gather 16 nodes with 16 hb loads in flight.
__global__ void __launch_bounds__(64)
sort_gather_kernel(const unsigned long long* __restrict__ binned,
                   const int* __restrict__ bin_cursor,
                   const unsigned* __restrict__ hb,
                   const int* __restrict__ ovf_cnt, const int* __restrict__ ovf_d,
                   const int* __restrict__ ovf_s, const float* __restrict__ ovf_w,
                   float* __restrict__ out, int N) {
    __shared__ unsigned hist[NODES_PER_BIN];
    __shared__ unsigned padoff[NODES_PER_BIN];
    __shared__ unsigned cur[NODES_PER_BIN];
    __shared__ unsigned csr_l[CSR_CAP];

    int b = blockIdx.x;
    int t = threadIdx.x;                    // 0..63 (one wave)
    int cnt = min(bin_cursor[b], BCAP);
    size_t rbase = (size_t)b * BCAP;

    if (t < NODES_PER_BIN) { hist[t] = 0; cur[t] = 0; }
    for (int i = t; i < CSR_CAP; i += 64) csr_l[i] = 0;   // pad slots = no-op edges
    __syncthreads();

    // pass 1: histogram (region ~1.5KB, L2-hot for pass 2)
    for (int i = t; i < cnt; i += 64)
        atomicAdd(&hist[(int)(binned[rbase + i] >> 32)], 1u);
    __syncthreads();

    // exclusive scan of x16-padded counts: 16 values, lanes 0-15 shuffle scan
    unsigned pc = 0, val = 0;
    if (t < NODES_PER_BIN) { pc = (hist[t] + 15u) & ~15u; val = pc; }
    #pragma unroll
    for (int off = 1; off < NODES_PER_BIN; off <<= 1) {
        unsigned u = __shfl_up(val, off, 64);
        if (t >= off) val += u;
    }
    if (t < NODES_PER_BIN) padoff[t] = val - pc;          // exclusive
    __syncthreads();

    // pass 2: reorder into LDS padded CSR
    for (int i = t; i < cnt; i += 64) {
        unsigned long long e = binned[rbase + i];
        int l = (int)(e >> 32);
        unsigned p = padoff[l] + atomicAdd(&cur[l], 1u);
        csr_l[p] = (unsigned)e;
    }
    __syncthreads();

    // gather: wave walks its 16 nodes; 16 independent hb loads per batch
    int nodes = min(NODES_PER_BIN, N - (b << BIN_SHIFT));
    bool ovf_bin = bin_cursor[b] > BCAP;

    for (int l = 0; l < nodes; ++l) {
        unsigned base = padoff[l];
        unsigned mr = (hist[l] + 15u) & ~15u;
        float accx = 0.0f, accy = 0.0f;
        for (unsigned j = 0; j < mr; j += 16) {
            unsigned uu[16];
            unsigned vv[16];
            #pragma unroll
            for (int q = 0; q < 16; ++q) uu[q] = csr_l[base + j + q];
            #pragma unroll
            for (int q = 0; q < 16; ++q)
                vv[q] = hb[(size_t)(uu[q] >> 16) * 64 + t];
            #pragma unroll
            for (int q = 0; q < 16; ++q) {
                float wf = __uint_as_float(uu[q] << 16);
                accx += __uint_as_float(vv[q] << 16) * wf;
                accy += __uint_as_float(vv[q] & 0xffff0000u) * wf;
            }
        }
        int node = (b << BIN_SHIFT) + l;
        if (ovf_bin) {                             // expected: never
            int oc = min(*ovf_cnt, OVF_CAP);
            for (int o = 0; o < oc; ++o) {
                if (ovf_d[o] == node) {
                    float we = ovf_w[o];
                    unsigned v = hb[(size_t)ovf_s[o] * 64 + t];
                    accx += __uint_as_float(v << 16) * we;
                    accy += __uint_as_float(v & 0xffff0000u) * we;
                }
            }
        }
        f2v r;
        r.x = accx; r.y = accy;
        __builtin_nontemporal_store(r, (f2v*)(out + (size_t)node * D_FEAT) + t);
    }
}

// ================== FALLBACK PATH: compact CSR (fp32, exact) ==================

__global__ void degree_kernel(const int* __restrict__ dst, int* __restrict__ deg, int E) {
    int e = blockIdx.x * blockDim.x + threadIdx.x;
    if (e >= E) return;
    atomicAdd(&deg[dst[e]], 1);
}

__global__ void scan_blocks(const int* __restrict__ deg, int* __restrict__ offs,
                            int* __restrict__ blockSums, int N) {
    __shared__ int tmp[256];
    int tid = threadIdx.x;
    int gid = blockIdx.x * 256 + tid;
    int v = (gid < N) ? deg[gid] : 0;
    tmp[tid] = v;
    __syncthreads();
    for (int off = 1; off < 256; off <<= 1) {
        int t = (tid >= off) ? tmp[tid - off] : 0;
        __syncthreads();
        tmp[tid] += t;
        __syncthreads();
    }
    if (gid < N) offs[gid] = tmp[tid] - v;
    if (tid == 255) blockSums[blockIdx.x] = tmp[255];
}

__global__ void scan_sums(int* __restrict__ blockSums, int* __restrict__ blockOffs, int nb) {
    __shared__ int tmp[256];
    int tid = threadIdx.x;
    int v = (tid < nb) ? blockSums[tid] : 0;
    tmp[tid] = v;
    __syncthreads();
    for (int off = 1; off < 256; off <<= 1) {
        int t = (tid >= off) ? tmp[tid - off] : 0;
        __syncthreads();
        tmp[tid] += t;
        __syncthreads();
    }
    if (tid < nb) blockOffs[tid] = tmp[tid] - v;
}

__global__ void scan_fixup(int* __restrict__ offs, const int* __restrict__ blockOffs,
                           int* __restrict__ cursor, int N) {
    int gid = blockIdx.x * 256 + threadIdx.x;
    if (gid >= N) return;
    int o = offs[gid] + blockOffs[blockIdx.x];
    offs[gid] = o;
    cursor[gid] = o;
}

__global__ void bucket_kernel(const int* __restrict__ src, const int* __restrict__ dst,
                              const float* __restrict__ dt, const float* __restrict__ norm,
                              const float* __restrict__ decay_lam,
                              int* __restrict__ cursor, float2* __restrict__ pairs, int E) {
    int e = blockIdx.x * blockDim.x + threadIdx.x;
    if (e >= E) return;
    float lam = fmaxf(decay_lam[0], 0.0f) + 1e-4f;
    float w = norm[e] * expf(-lam * dt[e]);
    int d = dst[e];
    int pos = atomicAdd(&cursor[d], 1);
    float2 p;
    p.x = __int_as_float(src[e]);
    p.y = w;
    pairs[pos] = p;
}

__global__ void __launch_bounds__(256)
gather_kernel(const float* __restrict__ h,
              const int* __restrict__ offs, const int* __restrict__ deg,
              const float2* __restrict__ pairs, float* __restrict__ out, int N) {
    int node = blockIdx.x * 4 + (threadIdx.x >> 6);
    if (node >= N) return;
    int lane = threadIdx.x & 63;
    int start = offs[node];
    int end = start + deg[node];
    float accx = 0.0f, accy = 0.0f;
    for (int j = start; j < end; ++j) {
        float2 p = pairs[j];
        int s = __float_as_int(p.x);
        float we = p.y;
        float2 v = ((const float2*)(h + (size_t)s * D_FEAT))[lane];
        accx += v.x * we;
        accy += v.y * we;
    }
    float2 r; r.x = accx; r.y = accy;
    ((float2*)(out + (size_t)node * D_FEAT))[lane] = r;
}

extern "C" void kernel_launch(void* const* d_in, const int* in_sizes, int n_in,
                              void* d_out, int out_size, void* d_ws, size_t ws_size,
                              hipStream_t stream) {
    const float* h         = (const float*)d_in[0];
    const int*   src       = (const int*)d_in[1];
    const int*   dst       = (const int*)d_in[2];
    const float* dt        = (const float*)d_in[3];
    const float* norm      = (const float*)d_in[4];
    const float* decay_lam = (const float*)d_in[5];
    float* out = (float*)d_out;

    const int E  = in_sizes[1];
    const int HN = in_sizes[0];
    const int N  = out_size / D_FEAT;
    const int NB = (N + NODES_PER_BIN - 1) >> BIN_SHIFT;

    auto align64 = [](size_t x) { return (x + 63) & ~(size_t)63; };
    size_t sz_binc = align64((size_t)NB * 4);
    size_t sz_ovfc = 64;
    size_t sz_ovf  = align64((size_t)OVF_CAP * 4);
    size_t sz_binn = align64((size_t)NB * BCAP * 8);
    size_t sz_hb   = align64((size_t)HN * 2);
    size_t need = sz_binc + sz_ovfc + 3 * sz_ovf + sz_binn + sz_hb;

    if (ws_size >= need && N <= 65536 && (HN & 3) == 0 &&
        NB <= NB_MAX && E <= BINB * T1 * RMAX) {
        char* ws = (char*)d_ws;
        int* bin_cursor = (int*)ws;                 ws += sz_binc;
        int* ovf_cnt    = (int*)ws;                 ws += sz_ovfc;
        int* ovf_d      = (int*)ws;                 ws += sz_ovf;
        int* ovf_s      = (int*)ws;                 ws += sz_ovf;
        float* ovf_w    = (float*)ws;               ws += sz_ovf;
        unsigned long long* binned = (unsigned long long*)ws;  ws += sz_binn;
        unsigned* hb    = (unsigned*)ws;

        hipMemsetAsync(bin_cursor, 0, sz_binc + sz_ovfc, stream);

        const int HN4 = HN / 4;
        const int convBlocks = (HN4 + T1 - 1) / T1;
        conv_bin_kernel<<<convBlocks + BINB, T1, 0, stream>>>(
            h, src, dst, dt, norm, decay_lam, hb, bin_cursor, binned,
            ovf_cnt, ovf_d, ovf_s, ovf_w, E, HN4, convBlocks, NB);

        sort_gather_kernel<<<NB, 64, 0, stream>>>(
            binned, bin_cursor, hb, ovf_cnt, ovf_d, ovf_s, ovf_w, out, N);
    } else {
        // -------- fallback: compact CSR with hierarchical scan (fp32 exact) --------
        const int nb = (N + 255) / 256;
        char* ws = (char*)d_ws;
        int*    dega      = (int*)ws;     ws += (size_t)N * 4;
        int*    offsa     = (int*)ws;     ws += (size_t)N * 4;
        int*    cursor    = (int*)ws;     ws += (size_t)N * 4;
        int*    blockSums = (int*)ws;     ws += 256 * 4;
        int*    blockOffs = (int*)ws;     ws += 256 * 4;
        float2* pairs     = (float2*)ws;

        hipMemsetAsync(dega, 0, (size_t)N * 4, stream);
        degree_kernel<<<(E + 255) / 256, 256, 0, stream>>>(dst, dega, E);
        scan_blocks<<<nb, 256, 0, stream>>>(dega, offsa, blockSums, N);
        scan_sums<<<1, 256, 0, stream>>>(blockSums, blockOffs, nb);
        scan_fixup<<<nb, 256, 0, stream>>>(offsa, blockOffs, cursor, N);
        bucket_kernel<<<(E + 255) / 256, 256, 0, stream>>>(
            src, dst, dt, norm, decay_lam, cursor, pairs, E);
        gather_kernel<<<(N + 3) / 4, 256, 0, stream>>>(h, offsa, dega, pairs, out, N);
    }
}